// Round 8
// baseline (119.798 us; speedup 1.0000x reference)
//
#include <hip/hip_runtime.h>

#define H 512
#define V 50000

typedef float fx4 __attribute__((ext_vector_type(4)));

__device__ __forceinline__ float sigmoidf(float x) {
    return 1.0f / (1.0f + __expf(-x));
}

__device__ __forceinline__ float dot4(fx4 a, fx4 b) {
    return a.x * b.x + a.y * b.y + a.z * b.z + a.w * b.w;
}

__device__ __forceinline__ fx4 ntload4(const float* p) {
    return __builtin_nontemporal_load((const fx4*)p);
}

__device__ __forceinline__ fx4 ld4(const float* p) {
    return *(const fx4*)p;
}

// Kernel A: h3_new only. 256 blocks x 128 threads (2 waves), wave handles one row.
__global__ __launch_bounds__(128) void kA(
    const float* __restrict__ intervalX, const float* __restrict__ h3,
    const float* __restrict__ W_h3, const float* __restrict__ b_h3,
    const float* __restrict__ W_int, const float* __restrict__ b_int,
    float* __restrict__ out)
{
    const int tid  = threadIdx.x;
    const int wv   = tid >> 6;
    const int lane = tid & 63;
    const int r    = blockIdx.x * 2 + wv;

    const float* Wrow = W_h3 + (size_t)r * H;
    fx4 a0 = ld4(Wrow + lane * 4);
    fx4 a1 = ld4(Wrow + 256 + lane * 4);
    fx4 x0 = ld4(h3 + lane * 4);
    fx4 x1 = ld4(h3 + 256 + lane * 4);
    float p = dot4(a0, x0) + dot4(a1, x1);
    #pragma unroll
    for (int m = 32; m >= 1; m >>= 1) p += __shfl_xor(p, m, 64);

    if (lane == 0) {
        float pre = p + intervalX[0] * W_int[r] + b_int[r] + b_h3[r];
        out[V + H + r] = sigmoidf(pre);
    }
}

// Kernel B: fused hypernet + gated update (+ folded x_emb@Wx.T term).
// block j: h_new[j] = sigmoid( dot(x_emb,Wx[j]) + Bx[j] + b_ictx[j]
//                              + sum_k h[k]*sigmoid(dot(h3n, W_ctx[j*512+k,:]) + b_ctx[j*512+k]) )
// 512 blocks x 1024 threads (16 waves): wave w handles rows k = w*32 .. w*32+31.
// LLC strategy (WITHIN-block interleave): rows with k%4==0 use plain loads
// (global 128MB resident set, stable across replays); other rows nt-stream.
// kbase%32==0 so k&3==i&3 -> load type is compile-time under full unroll.
__global__ __launch_bounds__(1024) void kB(
    const int* __restrict__ inputX, const float* __restrict__ emb,
    const float* __restrict__ h, const float* __restrict__ W_ctx,
    const float* __restrict__ b_ctx, const float* __restrict__ h3n,
    const float* __restrict__ Wx, const float* __restrict__ Bx,
    const float* __restrict__ b_ictx, float* __restrict__ out)
{
    __shared__ float sh3[H];
    __shared__ float sh[H];
    __shared__ float sbc[H];
    __shared__ float red[16];

    const int tid = threadIdx.x;
    const int j   = blockIdx.x;
    const size_t base = (size_t)j * H;

    if (tid < H) {
        sh3[tid] = h3n[tid];
    } else {
        const int t = tid - H;
        sh[t]  = h[t];
        sbc[t] = b_ctx[base + t];
    }
    __syncthreads();

    const int wv   = tid >> 6;
    const int lane = tid & 63;

    const fx4 x0 = ld4(sh3 + lane * 4);
    const fx4 x1 = ld4(sh3 + 256 + lane * 4);

    float acc = 0.0f;

    if (wv == 0) {
        // folded input term: dot(x_emb, Wx[j,:]) + Bx[j] + b_ictx[j]
        const float* Wxrow = Wx + (size_t)j * H;
        const float* e = emb + (size_t)inputX[0] * H;
        fx4 a0 = ld4(Wxrow + lane * 4);
        fx4 a1 = ld4(Wxrow + 256 + lane * 4);
        float p = dot4(a0, ld4(e + lane * 4)) + dot4(a1, ld4(e + 256 + lane * 4));
        #pragma unroll
        for (int m = 32; m >= 1; m >>= 1) p += __shfl_xor(p, m, 64);
        acc += p + Bx[j] + b_ictx[j];   // only lane0's red[] entry is used
    }

    const int kbase = wv * 32;
    #pragma unroll
    for (int i = 0; i < 32; i += 2) {
        const int k0 = kbase + i;
        const float* W0 = W_ctx + (base + (size_t)k0) * H;
        const float* W1 = W0 + H;
        fx4 a0, a1;
        if ((i & 3) == 0) {            // k0 % 4 == 0: LLC-resident row
            a0 = ld4(W0 + lane * 4);
            a1 = ld4(W0 + 256 + lane * 4);
        } else {                       // streaming row
            a0 = ntload4(W0 + lane * 4);
            a1 = ntload4(W0 + 256 + lane * 4);
        }
        // row k0+1 is odd -> always streaming
        fx4 b0 = ntload4(W1 + lane * 4);
        fx4 b1 = ntload4(W1 + 256 + lane * 4);

        float p = dot4(a0, x0) + dot4(a1, x1);
        float q = dot4(b0, x0) + dot4(b1, x1);
        #pragma unroll
        for (int m = 32; m >= 1; m >>= 1) {
            p += __shfl_xor(p, m, 64);
            q += __shfl_xor(q, m, 64);
        }
        acc += sh[k0]     * sigmoidf(p + sbc[k0]);
        acc += sh[k0 + 1] * sigmoidf(q + sbc[k0 + 1]);
    }

    if (lane == 0) red[wv] = acc;
    __syncthreads();

    if (tid == 0) {
        float t = 0.0f;
        #pragma unroll
        for (int w = 0; w < 16; ++w) t += red[w];
        out[V + j] = sigmoidf(t);
    }
}

// Kernel C: logits = h_new @ fc_W.T + fc_b.
// 6250 blocks x 256 threads: block handles 8 rows, wave w rows 8b+2w .. +1.
// Plain loads: fc_W (100MB) is an LLC-residency candidate across replays.
__global__ __launch_bounds__(256) void kC(
    const float* __restrict__ h_new, const float* __restrict__ fc_W,
    const float* __restrict__ fc_b, float* __restrict__ out)
{
    __shared__ float shn[H];
    const int tid = threadIdx.x;
    shn[tid]       = h_new[tid];
    shn[tid + 256] = h_new[tid + 256];
    __syncthreads();

    const int wv   = tid >> 6;
    const int lane = tid & 63;
    const fx4 x0 = ld4(shn + lane * 4);
    const fx4 x1 = ld4(shn + 256 + lane * 4);

    const int v0 = blockIdx.x * 8 + wv * 2;   // 6250*8 = 50000 exactly
    const float* W0 = fc_W + (size_t)v0 * H;
    const float* W1 = W0 + H;
    fx4 a0 = ld4(W0 + lane * 4);
    fx4 a1 = ld4(W0 + 256 + lane * 4);
    fx4 b0 = ld4(W1 + lane * 4);
    fx4 b1 = ld4(W1 + 256 + lane * 4);
    float p = dot4(a0, x0) + dot4(a1, x1);
    float q = dot4(b0, x0) + dot4(b1, x1);
    #pragma unroll
    for (int m = 32; m >= 1; m >>= 1) {
        p += __shfl_xor(p, m, 64);
        q += __shfl_xor(q, m, 64);
    }
    if (lane == 0) {
        out[v0]     = p + fc_b[v0];
        out[v0 + 1] = q + fc_b[v0 + 1];
    }
}

extern "C" void kernel_launch(void* const* d_in, const int* in_sizes, int n_in,
                              void* d_out, int out_size, void* d_ws, size_t ws_size,
                              hipStream_t stream) {
    const int*   inputX    = (const int*)d_in[0];
    const float* intervalX = (const float*)d_in[3];
    const float* h         = (const float*)d_in[4];
    const float* h3        = (const float*)d_in[5];
    const float* emb       = (const float*)d_in[6];
    const float* W_h3      = (const float*)d_in[7];
    const float* b_h3      = (const float*)d_in[8];
    const float* W_int     = (const float*)d_in[9];
    const float* b_int     = (const float*)d_in[10];
    const float* W_ctx     = (const float*)d_in[11];
    const float* b_ctx     = (const float*)d_in[12];
    const float* b_ictx    = (const float*)d_in[13];
    const float* Wx        = (const float*)d_in[14];
    const float* Bx        = (const float*)d_in[15];
    const float* fc_W      = (const float*)d_in[16];
    const float* fc_b      = (const float*)d_in[17];

    float* out = (float*)d_out;          // [logits(50000) | h_new(512) | h3_new(512)]

    kA<<<256, 128, 0, stream>>>(intervalX, h3, W_h3, b_h3, W_int, b_int, out);
    kB<<<512, 1024, 0, stream>>>(inputX, emb, h, W_ctx, b_ctx, out + V + H,
                                 Wx, Bx, b_ictx, out);
    kC<<<6250, 256, 0, stream>>>(out + V, fc_W, fc_b, out);
}

// Round 9
// 112.347 us; speedup vs baseline: 1.0663x; 1.0663x over previous
//
#include <hip/hip_runtime.h>

#define H 512
#define V 50000

typedef float fx4 __attribute__((ext_vector_type(4)));

__device__ __forceinline__ float sigmoidf(float x) {
    return 1.0f / (1.0f + __expf(-x));
}

__device__ __forceinline__ float dot4(fx4 a, fx4 b) {
    return a.x * b.x + a.y * b.y + a.z * b.z + a.w * b.w;
}

__device__ __forceinline__ fx4 ntload4(const float* p) {
    return __builtin_nontemporal_load((const fx4*)p);
}

__device__ __forceinline__ fx4 ld4(const float* p) {
    return *(const fx4*)p;
}

// Kernel A: h3_new only. 256 blocks x 128 threads (2 waves), wave handles one row.
__global__ __launch_bounds__(128) void kA(
    const float* __restrict__ intervalX, const float* __restrict__ h3,
    const float* __restrict__ W_h3, const float* __restrict__ b_h3,
    const float* __restrict__ W_int, const float* __restrict__ b_int,
    float* __restrict__ out)
{
    const int tid  = threadIdx.x;
    const int wv   = tid >> 6;
    const int lane = tid & 63;
    const int r    = blockIdx.x * 2 + wv;

    const float* Wrow = W_h3 + (size_t)r * H;
    fx4 a0 = ld4(Wrow + lane * 4);
    fx4 a1 = ld4(Wrow + 256 + lane * 4);
    fx4 x0 = ld4(h3 + lane * 4);
    fx4 x1 = ld4(h3 + 256 + lane * 4);
    float p = dot4(a0, x0) + dot4(a1, x1);
    #pragma unroll
    for (int m = 32; m >= 1; m >>= 1) p += __shfl_xor(p, m, 64);

    if (lane == 0) {
        float pre = p + intervalX[0] * W_int[r] + b_int[r] + b_h3[r];
        out[V + H + r] = sigmoidf(pre);
    }
}

// Kernel B: fused hypernet + gated update (+ folded x_emb@Wx.T term).
// block j: h_new[j] = sigmoid( dot(x_emb,Wx[j]) + Bx[j] + b_ictx[j]
//                              + sum_k h[k]*sigmoid(dot(h3n, W_ctx[j*512+k,:]) + b_ctx[j*512+k]) )
// 512 blocks x 1024 threads (16 waves): wave w handles rows k = w*32 .. w*32+31.
// LLC strategy: BLOCK-granular (within-wave mixing measured -6us, R8).
// Fast set (plain loads, ~128MB replay-resident): (j&3) == ((j>>8)&1) —
// anti-correlated under both (2c,2c+1) and (c,c+256) CU pairings, so no CU
// holds two fast blocks -> balanced tail. Other blocks: nt streaming.
__global__ __launch_bounds__(1024) void kB(
    const int* __restrict__ inputX, const float* __restrict__ emb,
    const float* __restrict__ h, const float* __restrict__ W_ctx,
    const float* __restrict__ b_ctx, const float* __restrict__ h3n,
    const float* __restrict__ Wx, const float* __restrict__ Bx,
    const float* __restrict__ b_ictx, float* __restrict__ out)
{
    __shared__ float sh3[H];
    __shared__ float sh[H];
    __shared__ float sbc[H];
    __shared__ float red[16];

    const int tid = threadIdx.x;
    const int j   = blockIdx.x;
    const size_t base = (size_t)j * H;

    if (tid < H) {
        sh3[tid] = h3n[tid];
    } else {
        const int t = tid - H;
        sh[t]  = h[t];
        sbc[t] = b_ctx[base + t];
    }
    __syncthreads();

    const int wv   = tid >> 6;
    const int lane = tid & 63;

    const fx4 x0 = ld4(sh3 + lane * 4);
    const fx4 x1 = ld4(sh3 + 256 + lane * 4);

    float acc = 0.0f;

    if (wv == 0) {
        // folded input term: dot(x_emb, Wx[j,:]) + Bx[j] + b_ictx[j]
        const float* Wxrow = Wx + (size_t)j * H;
        const float* e = emb + (size_t)inputX[0] * H;
        fx4 a0 = ld4(Wxrow + lane * 4);
        fx4 a1 = ld4(Wxrow + 256 + lane * 4);
        float p = dot4(a0, ld4(e + lane * 4)) + dot4(a1, ld4(e + 256 + lane * 4));
        #pragma unroll
        for (int m = 32; m >= 1; m >>= 1) p += __shfl_xor(p, m, 64);
        acc += p + Bx[j] + b_ictx[j];   // only lane0's red[] entry is used
    }

    const int kbase = wv * 32;
    if ((j & 3) == ((j >> 8) & 1)) {
        // LLC-resident quarter: plain loads
        for (int i = 0; i < 32; i += 2) {
            const int k0 = kbase + i;
            const float* W0 = W_ctx + (base + (size_t)k0) * H;
            const float* W1 = W0 + H;
            fx4 a0 = ld4(W0 + lane * 4);
            fx4 a1 = ld4(W0 + 256 + lane * 4);
            fx4 b0 = ld4(W1 + lane * 4);
            fx4 b1 = ld4(W1 + 256 + lane * 4);
            float p = dot4(a0, x0) + dot4(a1, x1);
            float q = dot4(b0, x0) + dot4(b1, x1);
            #pragma unroll
            for (int m = 32; m >= 1; m >>= 1) {
                p += __shfl_xor(p, m, 64);
                q += __shfl_xor(q, m, 64);
            }
            acc += sh[k0]     * sigmoidf(p + sbc[k0]);
            acc += sh[k0 + 1] * sigmoidf(q + sbc[k0 + 1]);
        }
    } else {
        // streaming three-quarters: nt (evict-first) loads
        for (int i = 0; i < 32; i += 2) {
            const int k0 = kbase + i;
            const float* W0 = W_ctx + (base + (size_t)k0) * H;
            const float* W1 = W0 + H;
            fx4 a0 = ntload4(W0 + lane * 4);
            fx4 a1 = ntload4(W0 + 256 + lane * 4);
            fx4 b0 = ntload4(W1 + lane * 4);
            fx4 b1 = ntload4(W1 + 256 + lane * 4);
            float p = dot4(a0, x0) + dot4(a1, x1);
            float q = dot4(b0, x0) + dot4(b1, x1);
            #pragma unroll
            for (int m = 32; m >= 1; m >>= 1) {
                p += __shfl_xor(p, m, 64);
                q += __shfl_xor(q, m, 64);
            }
            acc += sh[k0]     * sigmoidf(p + sbc[k0]);
            acc += sh[k0 + 1] * sigmoidf(q + sbc[k0 + 1]);
        }
    }

    if (lane == 0) red[wv] = acc;
    __syncthreads();

    if (tid == 0) {
        float t = 0.0f;
        #pragma unroll
        for (int w = 0; w < 16; ++w) t += red[w];
        out[V + j] = sigmoidf(t);
    }
}

// Kernel C: logits = h_new @ fc_W.T + fc_b.
// 6250 blocks x 256 threads: block handles 8 rows, wave w rows 8b+2w .. +1.
// Plain loads: fc_W (100MB) is an LLC-residency candidate across replays.
__global__ __launch_bounds__(256) void kC(
    const float* __restrict__ h_new, const float* __restrict__ fc_W,
    const float* __restrict__ fc_b, float* __restrict__ out)
{
    __shared__ float shn[H];
    const int tid = threadIdx.x;
    shn[tid]       = h_new[tid];
    shn[tid + 256] = h_new[tid + 256];
    __syncthreads();

    const int wv   = tid >> 6;
    const int lane = tid & 63;
    const fx4 x0 = ld4(shn + lane * 4);
    const fx4 x1 = ld4(shn + 256 + lane * 4);

    const int v0 = blockIdx.x * 8 + wv * 2;   // 6250*8 = 50000 exactly
    const float* W0 = fc_W + (size_t)v0 * H;
    const float* W1 = W0 + H;
    fx4 a0 = ld4(W0 + lane * 4);
    fx4 a1 = ld4(W0 + 256 + lane * 4);
    fx4 b0 = ld4(W1 + lane * 4);
    fx4 b1 = ld4(W1 + 256 + lane * 4);
    float p = dot4(a0, x0) + dot4(a1, x1);
    float q = dot4(b0, x0) + dot4(b1, x1);
    #pragma unroll
    for (int m = 32; m >= 1; m >>= 1) {
        p += __shfl_xor(p, m, 64);
        q += __shfl_xor(q, m, 64);
    }
    if (lane == 0) {
        out[v0]     = p + fc_b[v0];
        out[v0 + 1] = q + fc_b[v0 + 1];
    }
}

extern "C" void kernel_launch(void* const* d_in, const int* in_sizes, int n_in,
                              void* d_out, int out_size, void* d_ws, size_t ws_size,
                              hipStream_t stream) {
    const int*   inputX    = (const int*)d_in[0];
    const float* intervalX = (const float*)d_in[3];
    const float* h         = (const float*)d_in[4];
    const float* h3        = (const float*)d_in[5];
    const float* emb       = (const float*)d_in[6];
    const float* W_h3      = (const float*)d_in[7];
    const float* b_h3      = (const float*)d_in[8];
    const float* W_int     = (const float*)d_in[9];
    const float* b_int     = (const float*)d_in[10];
    const float* W_ctx     = (const float*)d_in[11];
    const float* b_ctx     = (const float*)d_in[12];
    const float* b_ictx    = (const float*)d_in[13];
    const float* Wx        = (const float*)d_in[14];
    const float* Bx        = (const float*)d_in[15];
    const float* fc_W      = (const float*)d_in[16];
    const float* fc_b      = (const float*)d_in[17];

    float* out = (float*)d_out;          // [logits(50000) | h_new(512) | h3_new(512)]

    kA<<<256, 128, 0, stream>>>(intervalX, h3, W_h3, b_h3, W_int, b_int, out);
    kB<<<512, 1024, 0, stream>>>(inputX, emb, h, W_ctx, b_ctx, out + V + H,
                                 Wx, Bx, b_ictx, out);
    kC<<<6250, 256, 0, stream>>>(out + V, fc_W, fc_b, out);
}

// Round 10
// 108.715 us; speedup vs baseline: 1.1019x; 1.0334x over previous
//
#include <hip/hip_runtime.h>

#define H 512
#define V 50000

typedef float fx4 __attribute__((ext_vector_type(4)));

__device__ __forceinline__ float sigmoidf(float x) {
    return 1.0f / (1.0f + __expf(-x));
}

__device__ __forceinline__ float dot4(fx4 a, fx4 b) {
    return a.x * b.x + a.y * b.y + a.z * b.z + a.w * b.w;
}

__device__ __forceinline__ fx4 ntload4(const float* p) {
    return __builtin_nontemporal_load((const fx4*)p);
}

__device__ __forceinline__ fx4 ld4(const float* p) {
    return *(const fx4*)p;
}

// Kernel A: h3_new only. 256 blocks x 128 threads (2 waves), wave handles one row.
__global__ __launch_bounds__(128) void kA(
    const float* __restrict__ intervalX, const float* __restrict__ h3,
    const float* __restrict__ W_h3, const float* __restrict__ b_h3,
    const float* __restrict__ W_int, const float* __restrict__ b_int,
    float* __restrict__ out)
{
    const int tid  = threadIdx.x;
    const int wv   = tid >> 6;
    const int lane = tid & 63;
    const int r    = blockIdx.x * 2 + wv;

    const float* Wrow = W_h3 + (size_t)r * H;
    fx4 a0 = ld4(Wrow + lane * 4);
    fx4 a1 = ld4(Wrow + 256 + lane * 4);
    fx4 x0 = ld4(h3 + lane * 4);
    fx4 x1 = ld4(h3 + 256 + lane * 4);
    float p = dot4(a0, x0) + dot4(a1, x1);
    #pragma unroll
    for (int m = 32; m >= 1; m >>= 1) p += __shfl_xor(p, m, 64);

    if (lane == 0) {
        float pre = p + intervalX[0] * W_int[r] + b_int[r] + b_h3[r];
        out[V + H + r] = sigmoidf(pre);
    }
}

// Kernel B: fused hypernet + gated update (+ folded x_emb@Wx.T term).
// block j: h_new[j] = sigmoid( dot(x_emb,Wx[j]) + Bx[j] + b_ictx[j]
//                              + sum_k h[k]*sigmoid(dot(h3n, W_ctx[j*512+k,:]) + b_ctx[j*512+k]) )
// 512 blocks x 1024 threads (16 waves): wave w handles rows k = w*32 .. w*32+31,
// hand-unrolled x2: 4 loads in flight, 2 interleaved butterfly reduces.
// LLC: (j&3)==0 plain loads (128MB resident across replays), rest nt streaming.
// [R8: within-wave nt/plain mixing = -11us. R9: alternate fast-set = -4us.
//  Block-granular (j&3)==0 is the measured optimum.]
__global__ __launch_bounds__(1024) void kB(
    const int* __restrict__ inputX, const float* __restrict__ emb,
    const float* __restrict__ h, const float* __restrict__ W_ctx,
    const float* __restrict__ b_ctx, const float* __restrict__ h3n,
    const float* __restrict__ Wx, const float* __restrict__ Bx,
    const float* __restrict__ b_ictx, float* __restrict__ out)
{
    __shared__ float sh3[H];
    __shared__ float sh[H];
    __shared__ float sbc[H];
    __shared__ float red[16];

    const int tid = threadIdx.x;
    const int j   = blockIdx.x;
    const size_t base = (size_t)j * H;

    if (tid < H) {
        sh3[tid] = h3n[tid];
    } else {
        const int t = tid - H;
        sh[t]  = h[t];
        sbc[t] = b_ctx[base + t];
    }
    __syncthreads();

    const int wv   = tid >> 6;
    const int lane = tid & 63;

    const fx4 x0 = ld4(sh3 + lane * 4);
    const fx4 x1 = ld4(sh3 + 256 + lane * 4);

    float acc = 0.0f;

    if (wv == 0) {
        // folded input term: dot(x_emb, Wx[j,:]) + Bx[j] + b_ictx[j]
        const float* Wxrow = Wx + (size_t)j * H;
        const float* e = emb + (size_t)inputX[0] * H;
        fx4 a0 = ld4(Wxrow + lane * 4);
        fx4 a1 = ld4(Wxrow + 256 + lane * 4);
        float p = dot4(a0, ld4(e + lane * 4)) + dot4(a1, ld4(e + 256 + lane * 4));
        #pragma unroll
        for (int m = 32; m >= 1; m >>= 1) p += __shfl_xor(p, m, 64);
        acc += p + Bx[j] + b_ictx[j];   // only lane0's red[] entry is used
    }

    const int kbase = wv * 32;
    if ((j & 3) == 0) {
        // LLC-resident quarter: plain loads
        for (int i = 0; i < 32; i += 2) {
            const int k0 = kbase + i;
            const float* W0 = W_ctx + (base + (size_t)k0) * H;
            const float* W1 = W0 + H;
            fx4 a0 = ld4(W0 + lane * 4);
            fx4 a1 = ld4(W0 + 256 + lane * 4);
            fx4 b0 = ld4(W1 + lane * 4);
            fx4 b1 = ld4(W1 + 256 + lane * 4);
            float p = dot4(a0, x0) + dot4(a1, x1);
            float q = dot4(b0, x0) + dot4(b1, x1);
            #pragma unroll
            for (int m = 32; m >= 1; m >>= 1) {
                p += __shfl_xor(p, m, 64);
                q += __shfl_xor(q, m, 64);
            }
            acc += sh[k0]     * sigmoidf(p + sbc[k0]);
            acc += sh[k0 + 1] * sigmoidf(q + sbc[k0 + 1]);
        }
    } else {
        // streaming three-quarters: nt (evict-first) loads
        for (int i = 0; i < 32; i += 2) {
            const int k0 = kbase + i;
            const float* W0 = W_ctx + (base + (size_t)k0) * H;
            const float* W1 = W0 + H;
            fx4 a0 = ntload4(W0 + lane * 4);
            fx4 a1 = ntload4(W0 + 256 + lane * 4);
            fx4 b0 = ntload4(W1 + lane * 4);
            fx4 b1 = ntload4(W1 + 256 + lane * 4);
            float p = dot4(a0, x0) + dot4(a1, x1);
            float q = dot4(b0, x0) + dot4(b1, x1);
            #pragma unroll
            for (int m = 32; m >= 1; m >>= 1) {
                p += __shfl_xor(p, m, 64);
                q += __shfl_xor(q, m, 64);
            }
            acc += sh[k0]     * sigmoidf(p + sbc[k0]);
            acc += sh[k0 + 1] * sigmoidf(q + sbc[k0 + 1]);
        }
    }

    if (lane == 0) red[wv] = acc;
    __syncthreads();

    if (tid == 0) {
        float t = 0.0f;
        #pragma unroll
        for (int w = 0; w < 16; ++w) t += red[w];
        out[V + j] = sigmoidf(t);
    }
}

// Kernel C: logits = h_new @ fc_W.T + fc_b.
// 6250 blocks x 256 threads: block handles 8 rows, wave w rows 8b+2w .. +1.
// Plain loads: fc_W (100MB) is an LLC-residency candidate across replays.
__global__ __launch_bounds__(256) void kC(
    const float* __restrict__ h_new, const float* __restrict__ fc_W,
    const float* __restrict__ fc_b, float* __restrict__ out)
{
    __shared__ float shn[H];
    const int tid = threadIdx.x;
    shn[tid]       = h_new[tid];
    shn[tid + 256] = h_new[tid + 256];
    __syncthreads();

    const int wv   = tid >> 6;
    const int lane = tid & 63;
    const fx4 x0 = ld4(shn + lane * 4);
    const fx4 x1 = ld4(shn + 256 + lane * 4);

    const int v0 = blockIdx.x * 8 + wv * 2;   // 6250*8 = 50000 exactly
    const float* W0 = fc_W + (size_t)v0 * H;
    const float* W1 = W0 + H;
    fx4 a0 = ld4(W0 + lane * 4);
    fx4 a1 = ld4(W0 + 256 + lane * 4);
    fx4 b0 = ld4(W1 + lane * 4);
    fx4 b1 = ld4(W1 + 256 + lane * 4);
    float p = dot4(a0, x0) + dot4(a1, x1);
    float q = dot4(b0, x0) + dot4(b1, x1);
    #pragma unroll
    for (int m = 32; m >= 1; m >>= 1) {
        p += __shfl_xor(p, m, 64);
        q += __shfl_xor(q, m, 64);
    }
    if (lane == 0) {
        out[v0]     = p + fc_b[v0];
        out[v0 + 1] = q + fc_b[v0 + 1];
    }
}

extern "C" void kernel_launch(void* const* d_in, const int* in_sizes, int n_in,
                              void* d_out, int out_size, void* d_ws, size_t ws_size,
                              hipStream_t stream) {
    const int*   inputX    = (const int*)d_in[0];
    const float* intervalX = (const float*)d_in[3];
    const float* h         = (const float*)d_in[4];
    const float* h3        = (const float*)d_in[5];
    const float* emb       = (const float*)d_in[6];
    const float* W_h3      = (const float*)d_in[7];
    const float* b_h3      = (const float*)d_in[8];
    const float* W_int     = (const float*)d_in[9];
    const float* b_int     = (const float*)d_in[10];
    const float* W_ctx     = (const float*)d_in[11];
    const float* b_ctx     = (const float*)d_in[12];
    const float* b_ictx    = (const float*)d_in[13];
    const float* Wx        = (const float*)d_in[14];
    const float* Bx        = (const float*)d_in[15];
    const float* fc_W      = (const float*)d_in[16];
    const float* fc_b      = (const float*)d_in[17];

    float* out = (float*)d_out;          // [logits(50000) | h_new(512) | h3_new(512)]

    kA<<<256, 128, 0, stream>>>(intervalX, h3, W_h3, b_h3, W_int, b_int, out);
    kB<<<512, 1024, 0, stream>>>(inputX, emb, h, W_ctx, b_ctx, out + V + H,
                                 Wx, Bx, b_ictx, out);
    kC<<<6250, 256, 0, stream>>>(out + V, fc_W, fc_b, out);
}